// Round 1
// baseline (7932.671 us; speedup 1.0000x reference)
//
#include <hip/hip_runtime.h>
#include <math.h>

#define NB 16
#define NOBJ 128
#define NROLL 8

struct W {
  const float *rc0w,*rc0b,*rc1w,*rc1b,*rc2w,*rc2b;
  const float *at0w,*at0b,*at1w,*at1b,*at2w,*at2b;
  const float *af0w,*af0b,*af1w,*af1b,*af2w,*af2b;
  const float *o0w,*o0b,*o1w,*o1b;
  const float *sc0w,*sc0b,*sc1w,*sc1b;
};

__device__ __forceinline__ float fast_tanh(float x){
  x = fminf(fmaxf(x, -15.f), 15.f);
  float e = __expf(2.f * x);
  return __fdividef(e - 1.f, e + 1.f);
}

// ---------------------------------------------------------------------------
// encode: state_codes = concat(x, (x@se_w+se_b)[...,4:]); present = x;
// cur = state_codes[:, t=3]
// ---------------------------------------------------------------------------
__global__ __launch_bounds__(128)
void encode_kernel(const float* __restrict__ x, const float* __restrict__ sew,
                   const float* __restrict__ seb, float* __restrict__ present,
                   float* __restrict__ S0)
{
  int bt = blockIdx.x;        // b*4 + t
  int o  = threadIdx.x;       // 0..127
  const float* xv = x + (size_t)(bt * NOBJ + o) * 4;
  float x0 = xv[0], x1 = xv[1], x2 = xv[2], x3 = xv[3];
  float* pr = present + (size_t)(bt * NOBJ + o) * 4;
  pr[0] = x0; pr[1] = x1; pr[2] = x2; pr[3] = x3;
  int t = bt & 3, b = bt >> 2;
  if (t == 3) {
    float* s = S0 + (size_t)(b * NOBJ + o) * 32;
    s[0] = x0; s[1] = x1; s[2] = x2; s[3] = x3;
    #pragma unroll
    for (int k = 4; k < 32; k++)
      s[k] = seb[k] + x0*sew[k] + x1*sew[32+k] + x2*sew[64+k] + x3*sew[96+k];
  }
}

// ---------------------------------------------------------------------------
// per-object projections: P1r/P2r (rel layer-1 halves), P1a/P2a (att),
// self_dyn, positions.  Called with >=64 threads; s_sh holds state (32).
// ---------------------------------------------------------------------------
__device__ void project_body(int tid, int bo, const float* __restrict__ s_sh,
                             float* __restrict__ h_sh, const W& w,
                             float* __restrict__ SD,
                             float* __restrict__ P1R, float* __restrict__ P1A,
                             float* __restrict__ P2R, float* __restrict__ P2A,
                             float* __restrict__ PX, float* __restrict__ PY)
{
  int b = bo >> 7, o = bo & 127;
  if (tid < 64) {
    float a1r = w.rc0b[tid], a2r = 0.f, a1a = w.at0b[tid], a2a = 0.f;
    #pragma unroll
    for (int c = 0; c < 32; c++) {
      float sv = s_sh[c];
      a1r += sv * w.rc0w[c*64 + tid];
      a2r += sv * w.rc0w[(32+c)*64 + tid];
      a1a += sv * w.at0w[c*64 + tid];
      a2a += sv * w.at0w[(32+c)*64 + tid];
    }
    P1R[(size_t)bo*64 + tid] = a1r;
    P1A[(size_t)bo*64 + tid] = a1a;
    P2R[(size_t)(b*64 + tid)*NOBJ + o] = a2r;  // transposed [b][k][j]
    P2A[(size_t)(b*64 + tid)*NOBJ + o] = a2a;
  }
  if (tid < 32) {
    float acc = w.sc0b[tid];
    #pragma unroll
    for (int c = 0; c < 32; c++) acc += s_sh[c] * w.sc0w[c*32 + tid];
    h_sh[tid] = fmaxf(acc, 0.f);
  }
  __syncthreads();
  if (tid < 32) {
    float acc = w.sc1b[tid] + h_sh[tid];
    #pragma unroll
    for (int c = 0; c < 32; c++) acc += h_sh[c] * w.sc1w[c*32 + tid];
    SD[(size_t)bo*32 + tid] = acc;
  }
  if (tid == 0) { PX[bo] = s_sh[0]; PY[bo] = s_sh[1]; }
}

__global__ __launch_bounds__(64)
void project_kernel(const float* __restrict__ S, W w,
                    float* SD, float* P1R, float* P1A,
                    float* P2R, float* P2A, float* PX, float* PY)
{
  __shared__ float s_sh[32], h_sh[32];
  int bo = blockIdx.x, tid = threadIdx.x;
  if (tid < 32) s_sh[tid] = S[(size_t)bo*32 + tid];
  __syncthreads();
  project_body(tid, bo, s_sh, h_sh, w, SD, P1R, P1A, P2R, P2A, PX, PY);
}

// ---------------------------------------------------------------------------
// one rollout step.  block = (b,i), 128 threads = one per j.
// ---------------------------------------------------------------------------
__global__ __launch_bounds__(128)
void step_kernel(const float* __restrict__ S_in,  const float* __restrict__ SD_in,
                 const float* __restrict__ P1R_in, const float* __restrict__ P1A_in,
                 const float* __restrict__ P2R_in, const float* __restrict__ P2A_in,
                 const float* __restrict__ PX_in,  const float* __restrict__ PY_in,
                 float* __restrict__ S_out, float* __restrict__ SD_out,
                 float* __restrict__ P1R_out, float* __restrict__ P1A_out,
                 float* __restrict__ P2R_out, float* __restrict__ P2A_out,
                 float* __restrict__ PX_out, float* __restrict__ PY_out,
                 W w, float* __restrict__ out_roll, int tstep)
{
  int bi = blockIdx.x;            // b*128 + i
  int b = bi >> 7, i = bi & 127;
  int tid = threadIdx.x;          // j
  __shared__ float s_sh[32], snew_sh[32], h_sh[32];
  __shared__ float red[2][32];
  __shared__ float v0_sh[32], v1_sh[32], v2_sh[32];

  if (tid < 32) s_sh[tid] = S_in[(size_t)bi*32 + tid];
  __syncthreads();

  const float* p1r = P1R_in + (size_t)bi*64;
  const float* p1a = P1A_in + (size_t)bi*64;
  float px_i = s_sh[0], py_i = s_sh[1];
  int j = tid;
  float px_j = PX_in[b*NOBJ + j], py_j = PY_in[b*NOBJ + j];
  float dx = px_i - px_j, dy = py_i - py_j;
  float dist = sqrtf(dx*dx + dy*dy + 1e-10f);

  // ---- attention path: 67->64 (hoisted) -> tanh -> 64->32 tanh -> 32->1 exp
  float t1[64];
  #pragma unroll
  for (int k = 0; k < 64; k++) {
    float v = p1a[k] + P2A_in[(size_t)(b*64 + k)*NOBJ + j]
            + dist * w.at0w[64*64 + k] + dx * w.at0w[65*64 + k] + dy * w.at0w[66*64 + k];
    t1[k] = fast_tanh(v);
  }
  float att = w.at2b[0];
  #pragma unroll
  for (int k2 = 0; k2 < 32; k2++) {
    float acc = w.at1b[k2];
    #pragma unroll
    for (int k = 0; k < 64; k++) acc += t1[k] * w.at1w[k*32 + k2];
    att += fast_tanh(acc) * w.at2w[k2];
  }
  att = __expf(att);
  if (j == i) att = 0.f;   // diag mask

  // ---- relation path: 67->64 relu (hoisted) -> 64->32 relu -> 32->32 + res
  float r1[64];
  #pragma unroll
  for (int k = 0; k < 64; k++) {
    float v = p1r[k] + P2R_in[(size_t)(b*64 + k)*NOBJ + j]
            + dist * w.rc0w[64*64 + k] + dx * w.rc0w[65*64 + k] + dy * w.rc0w[66*64 + k];
    r1[k] = fmaxf(v, 0.f);
  }
  float rel[32];
  #pragma unroll
  for (int c = 0; c < 32; c++) rel[c] = w.rc2b[c];
  #pragma unroll
  for (int k2 = 0; k2 < 32; k2++) {
    float acc = w.rc1b[k2];
    #pragma unroll
    for (int k = 0; k < 64; k++) acc += r1[k] * w.rc1w[k*32 + k2];
    float r2v = fmaxf(acc, 0.f);
    rel[k2] += r2v;                      // residual  (rc2 out + r2)
    #pragma unroll
    for (int c = 0; c < 32; c++) rel[c] += r2v * w.rc2w[k2*32 + c];
  }
  #pragma unroll
  for (int c = 0; c < 32; c++) rel[c] *= att;

  // ---- reduce rel[32] over the 128 j-threads (wave butterfly + LDS)
  #pragma unroll
  for (int c = 0; c < 32; c++) {
    float v = rel[c];
    v += __shfl_xor(v, 1);  v += __shfl_xor(v, 2);  v += __shfl_xor(v, 4);
    v += __shfl_xor(v, 8);  v += __shfl_xor(v, 16); v += __shfl_xor(v, 32);
    rel[c] = v;
  }
  int wv = tid >> 6, lane = tid & 63;
  if (lane == 0) {
    #pragma unroll
    for (int c = 0; c < 32; c++) red[wv][c] = rel[c];
  }
  __syncthreads();

  // ---- per-object tail (32 threads, LDS intermediates)
  if (tid < 32) {
    float d = SD_in[(size_t)bi*32 + tid] + red[0][tid] + red[1][tid];
    v0_sh[tid] = d;                                    // dyn
  }
  __syncthreads();
  if (tid < 32) {
    float acc = w.af0b[tid];
    for (int k = 0; k < 32; k++) acc += v0_sh[k] * w.af0w[k*32 + tid];
    v1_sh[tid] = fast_tanh(acc);                       // aff1
  }
  __syncthreads();
  if (tid < 32) {
    float acc = w.af1b[tid];
    for (int k = 0; k < 32; k++) acc += v1_sh[k] * w.af1w[k*32 + tid];
    v2_sh[tid] = fast_tanh(acc) + v1_sh[tid];          // aff2
  }
  __syncthreads();
  if (tid < 32) {
    float acc = w.af2b[tid];
    for (int k = 0; k < 32; k++) acc += v2_sh[k] * w.af2w[k*32 + tid];
    v0_sh[tid] = acc;                                  // aff3 (reuse)
  }
  __syncthreads();
  if (tid < 32) {
    float acc = w.o0b[tid];
    for (int k = 0; k < 32; k++) acc += v0_sh[k] * w.o0w[k*32 + tid];
    for (int k = 0; k < 32; k++) acc += s_sh[k]  * w.o0w[(32+k)*32 + tid];
    v1_sh[tid] = fast_tanh(acc);                       // out1 (reuse)
  }
  __syncthreads();
  if (tid < 32) {
    float acc = w.o1b[tid] + v1_sh[tid];
    for (int k = 0; k < 32; k++) acc += v1_sh[k] * w.o1w[k*32 + tid];
    if (tid < 2) acc += s_sh[tid];
    snew_sh[tid] = acc;
    S_out[(size_t)bi*32 + tid] = acc;
    if (tid < 4)
      out_roll[(size_t)((b*NROLL + tstep)*NOBJ + i)*4 + tid] = acc;
  }
  __syncthreads();

  // ---- fused projections of the NEW state for the next step
  project_body(tid, bi, snew_sh, h_sh, w,
               SD_out, P1R_out, P1A_out, P2R_out, P2A_out, PX_out, PY_out);
}

// ---------------------------------------------------------------------------
extern "C" void kernel_launch(void* const* d_in, const int* in_sizes, int n_in,
                              void* d_out, int out_size, void* d_ws, size_t ws_size,
                              hipStream_t stream)
{
  const float* x    = (const float*)d_in[0];
  const float* sew  = (const float*)d_in[1];
  const float* seb  = (const float*)d_in[2];
  W w;
  w.sc0w=(const float*)d_in[3];  w.sc0b=(const float*)d_in[4];
  w.sc1w=(const float*)d_in[5];  w.sc1b=(const float*)d_in[6];
  w.rc0w=(const float*)d_in[7];  w.rc0b=(const float*)d_in[8];
  w.rc1w=(const float*)d_in[9];  w.rc1b=(const float*)d_in[10];
  w.rc2w=(const float*)d_in[11]; w.rc2b=(const float*)d_in[12];
  w.at0w=(const float*)d_in[13]; w.at0b=(const float*)d_in[14];
  w.at1w=(const float*)d_in[15]; w.at1b=(const float*)d_in[16];
  w.at2w=(const float*)d_in[17]; w.at2b=(const float*)d_in[18];
  w.af0w=(const float*)d_in[19]; w.af0b=(const float*)d_in[20];
  w.af1w=(const float*)d_in[21]; w.af1b=(const float*)d_in[22];
  w.af2w=(const float*)d_in[23]; w.af2b=(const float*)d_in[24];
  w.o0w =(const float*)d_in[25]; w.o0b =(const float*)d_in[26];
  w.o1w =(const float*)d_in[27]; w.o1b =(const float*)d_in[28];

  float* out = (float*)d_out;
  float* out_roll    = out;                              // (16,8,128,4)
  float* out_present = out + NB*NROLL*NOBJ*4;            // (16,4,128,4)

  float* ws = (float*)d_ws;
  size_t off = 0;
  auto alloc = [&](size_t n){ float* p = ws + off; off += n; return p; };
  float* S[2]   = { alloc(NB*NOBJ*32), alloc(NB*NOBJ*32) };
  float* SD[2]  = { alloc(NB*NOBJ*32), alloc(NB*NOBJ*32) };
  float* P1R[2] = { alloc(NB*NOBJ*64), alloc(NB*NOBJ*64) };
  float* P1A[2] = { alloc(NB*NOBJ*64), alloc(NB*NOBJ*64) };
  float* P2R[2] = { alloc(NB*64*NOBJ), alloc(NB*64*NOBJ) };
  float* P2A[2] = { alloc(NB*64*NOBJ), alloc(NB*64*NOBJ) };
  float* PX[2]  = { alloc(NB*NOBJ),    alloc(NB*NOBJ) };
  float* PY[2]  = { alloc(NB*NOBJ),    alloc(NB*NOBJ) };
  (void)ws_size; (void)in_sizes; (void)n_in; (void)out_size;

  hipLaunchKernelGGL(encode_kernel, dim3(NB*4), dim3(NOBJ), 0, stream,
                     x, sew, seb, out_present, S[0]);
  hipLaunchKernelGGL(project_kernel, dim3(NB*NOBJ), dim3(64), 0, stream,
                     S[0], w, SD[0], P1R[0], P1A[0], P2R[0], P2A[0], PX[0], PY[0]);

  for (int t = 0; t < NROLL; t++) {
    int a = t & 1, oo = 1 - a;
    hipLaunchKernelGGL(step_kernel, dim3(NB*NOBJ), dim3(128), 0, stream,
                       S[a], SD[a], P1R[a], P1A[a], P2R[a], P2A[a], PX[a], PY[a],
                       S[oo], SD[oo], P1R[oo], P1A[oo], P2R[oo], P2A[oo], PX[oo], PY[oo],
                       w, out_roll, t);
  }
}

// Round 2
// 1170.758 us; speedup vs baseline: 6.7757x; 6.7757x over previous
//
#include <hip/hip_runtime.h>
#include <math.h>

#define NB 16
#define NOBJ 128
#define NROLL 8

struct W {
  const float *rc0w,*rc0b,*rc1w,*rc1b,*rc2w,*rc2b;
  const float *at0w,*at0b,*at1w,*at1b,*at2w,*at2b;
  const float *af0w,*af0b,*af1w,*af1b,*af2w,*af2b;
  const float *o0w,*o0b,*o1w,*o1b;
  const float *sc0w,*sc0b,*sc1w,*sc1b;
};

__device__ __forceinline__ float fast_tanh(float x){
  x = fminf(fmaxf(x, -15.f), 15.f);
  float e = __expf(2.f * x);
  return __fdividef(e - 1.f, e + 1.f);
}

// ---------------------------------------------------------------------------
// encode: state_codes = concat(x, (x@se_w+se_b)[...,4:]); present = x;
// cur = state_codes[:, t=3]
// ---------------------------------------------------------------------------
__global__ __launch_bounds__(128)
void encode_kernel(const float* __restrict__ x, const float* __restrict__ sew,
                   const float* __restrict__ seb, float* __restrict__ present,
                   float* __restrict__ S0)
{
  int bt = blockIdx.x;        // b*4 + t
  int o  = threadIdx.x;       // 0..127
  const float* xv = x + (size_t)(bt * NOBJ + o) * 4;
  float x0 = xv[0], x1 = xv[1], x2 = xv[2], x3 = xv[3];
  float* pr = present + (size_t)(bt * NOBJ + o) * 4;
  pr[0] = x0; pr[1] = x1; pr[2] = x2; pr[3] = x3;
  int t = bt & 3, b = bt >> 2;
  if (t == 3) {
    float* s = S0 + (size_t)(b * NOBJ + o) * 32;
    s[0] = x0; s[1] = x1; s[2] = x2; s[3] = x3;
    #pragma unroll
    for (int k = 4; k < 32; k++)
      s[k] = seb[k] + x0*sew[k] + x1*sew[32+k] + x2*sew[64+k] + x3*sew[96+k];
  }
}

// ---------------------------------------------------------------------------
// per-object projections: P1r/P2r (rel layer-1 halves), P1a/P2a (att),
// self_dyn, positions.
// ---------------------------------------------------------------------------
__device__ void project_body(int tid, int bo, const float* __restrict__ s_sh,
                             float* __restrict__ h_sh, const W& w,
                             float* __restrict__ SD,
                             float* __restrict__ P1R, float* __restrict__ P1A,
                             float* __restrict__ P2R, float* __restrict__ P2A,
                             float* __restrict__ PX, float* __restrict__ PY)
{
  int b = bo >> 7, o = bo & 127;
  if (tid < 64) {
    float a1r = w.rc0b[tid], a2r = 0.f, a1a = w.at0b[tid], a2a = 0.f;
    #pragma unroll
    for (int c = 0; c < 32; c++) {
      float sv = s_sh[c];
      a1r += sv * w.rc0w[c*64 + tid];
      a2r += sv * w.rc0w[(32+c)*64 + tid];
      a1a += sv * w.at0w[c*64 + tid];
      a2a += sv * w.at0w[(32+c)*64 + tid];
    }
    P1R[(size_t)bo*64 + tid] = a1r;
    P1A[(size_t)bo*64 + tid] = a1a;
    P2R[(size_t)(b*64 + tid)*NOBJ + o] = a2r;  // transposed [b][k][j]
    P2A[(size_t)(b*64 + tid)*NOBJ + o] = a2a;
  }
  if (tid < 32) {
    float acc = w.sc0b[tid];
    #pragma unroll
    for (int c = 0; c < 32; c++) acc += s_sh[c] * w.sc0w[c*32 + tid];
    h_sh[tid] = fmaxf(acc, 0.f);
  }
  __syncthreads();
  if (tid < 32) {
    float acc = w.sc1b[tid] + h_sh[tid];
    #pragma unroll
    for (int c = 0; c < 32; c++) acc += h_sh[c] * w.sc1w[c*32 + tid];
    SD[(size_t)bo*32 + tid] = acc;
  }
  if (tid == 0) { PX[bo] = s_sh[0]; PY[bo] = s_sh[1]; }
}

__global__ __launch_bounds__(64)
void project_kernel(const float* __restrict__ S, W w,
                    float* SD, float* P1R, float* P1A,
                    float* P2R, float* P2A, float* PX, float* PY)
{
  __shared__ float s_sh[32], h_sh[32];
  int bo = blockIdx.x, tid = threadIdx.x;
  if (tid < 32) s_sh[tid] = S[(size_t)bo*32 + tid];
  __syncthreads();
  project_body(tid, bo, s_sh, h_sh, w, SD, P1R, P1A, P2R, P2A, PX, PY);
}

// ---------------------------------------------------------------------------
// one rollout step.  block = (b,i), 128 threads = one per j.
// Pair-loop weights staged in LDS; inner GEMVs: rolled outer / unrolled inner,
// uniform-address ds_read (broadcast, conflict-free).
// ---------------------------------------------------------------------------
__global__ __launch_bounds__(128)
void step_kernel(const float* __restrict__ S_in,  const float* __restrict__ SD_in,
                 const float* __restrict__ P1R_in, const float* __restrict__ P1A_in,
                 const float* __restrict__ P2R_in, const float* __restrict__ P2A_in,
                 const float* __restrict__ PX_in,  const float* __restrict__ PY_in,
                 float* __restrict__ S_out, float* __restrict__ SD_out,
                 float* __restrict__ P1R_out, float* __restrict__ P1A_out,
                 float* __restrict__ P2R_out, float* __restrict__ P2A_out,
                 float* __restrict__ PX_out, float* __restrict__ PY_out,
                 W w, float* __restrict__ out_roll, int tstep)
{
  __shared__ __align__(16) float smem[6016];
  float* wA      = smem;          // 2048  at1w [64][32]
  float* wR      = smem + 2048;   // 2048  rc1w [64][32]
  float* wC      = smem + 4096;   // 1024  rc2w + I
  float* geoA    = smem + 5120;   // 192   at0w rows 64..66
  float* geoR    = smem + 5312;   // 192   rc0w rows 64..66
  float* bA      = smem + 5504;   // 32    at1b
  float* bR      = smem + 5536;   // 32    rc1b
  float* bC      = smem + 5568;   // 32    rc2b
  float* wT2     = smem + 5600;   // 32    at2w
  float* p1a_sh  = smem + 5632;   // 64
  float* p1r_sh  = smem + 5696;   // 64
  float* s_sh    = smem + 5760;   // 32
  float* snew_sh = smem + 5792;   // 32
  float* h_sh    = smem + 5824;   // 32
  float* red     = smem + 5856;   // 64 (2 waves x 32)
  float* v0_sh   = smem + 5920;   // 32
  float* v1_sh   = smem + 5952;   // 32
  float* v2_sh   = smem + 5984;   // 32

  int bi = blockIdx.x;            // b*128 + i
  int b = bi >> 7, i = bi & 127;
  int tid = threadIdx.x;          // j
  int j = tid;

  // ---- stage weights & per-block vectors into LDS (vectorized) ----
  for (int idx = tid; idx < 512; idx += 128)
    ((float4*)wA)[idx] = ((const float4*)w.at1w)[idx];
  for (int idx = tid; idx < 512; idx += 128)
    ((float4*)wR)[idx] = ((const float4*)w.rc1w)[idx];
  for (int idx = tid; idx < 1024; idx += 128) {
    int k2 = idx >> 5, c = idx & 31;
    wC[idx] = w.rc2w[idx] + ((k2 == c) ? 1.f : 0.f);   // fold +I residual
  }
  if (tid < 48)
    ((float4*)geoA)[tid] = ((const float4*)(w.at0w + 64*64))[tid];
  else if (tid >= 64 && tid < 112)
    ((float4*)geoR)[tid-64] = ((const float4*)(w.rc0w + 64*64))[tid-64];
  if (tid < 32) { bA[tid]=w.at1b[tid]; bR[tid]=w.rc1b[tid];
                  bC[tid]=w.rc2b[tid]; wT2[tid]=w.at2w[tid]; }
  if (tid < 64) { p1a_sh[tid] = P1A_in[(size_t)bi*64 + tid];
                  p1r_sh[tid] = P1R_in[(size_t)bi*64 + tid]; }
  if (tid >= 96) s_sh[tid-96] = S_in[(size_t)bi*32 + (tid-96)];
  __syncthreads();

  float px_i = s_sh[0], py_i = s_sh[1];
  float px_j = PX_in[b*NOBJ + j], py_j = PY_in[b*NOBJ + j];
  float dx = px_i - px_j, dy = py_i - py_j;
  float dist = sqrtf(dx*dx + dy*dy + 1e-10f);

  const float* P2A_p = P2A_in + (size_t)b*64*NOBJ + j;
  const float* P2R_p = P2R_in + (size_t)b*64*NOBJ + j;

  // ---- attention path ----
  float t1[64];
  #pragma unroll
  for (int k = 0; k < 64; k++) {
    float v = p1a_sh[k] + P2A_p[k*NOBJ]
            + dist*geoA[k] + dx*geoA[64+k] + dy*geoA[128+k];
    t1[k] = fast_tanh(v);
  }
  float att_acc = w.at2b[0];
  #pragma unroll 1
  for (int k2 = 0; k2 < 32; k2 += 4) {
    float4 acc = *(const float4*)&bA[k2];
    #pragma unroll
    for (int k = 0; k < 64; k++) {
      float4 wv = *(const float4*)&wA[k*32 + k2];
      acc.x = fmaf(t1[k], wv.x, acc.x);
      acc.y = fmaf(t1[k], wv.y, acc.y);
      acc.z = fmaf(t1[k], wv.z, acc.z);
      acc.w = fmaf(t1[k], wv.w, acc.w);
    }
    att_acc += fast_tanh(acc.x)*wT2[k2]   + fast_tanh(acc.y)*wT2[k2+1]
             + fast_tanh(acc.z)*wT2[k2+2] + fast_tanh(acc.w)*wT2[k2+3];
  }
  float att = __expf(att_acc);
  if (j == i) att = 0.f;   // diag mask

  // ---- relation path ----
  float r1[64];
  #pragma unroll
  for (int k = 0; k < 64; k++) {
    float v = p1r_sh[k] + P2R_p[k*NOBJ]
            + dist*geoR[k] + dx*geoR[64+k] + dy*geoR[128+k];
    r1[k] = fmaxf(v, 0.f);
  }
  float4 rel4[8];
  #pragma unroll
  for (int cg = 0; cg < 8; cg++) rel4[cg] = ((const float4*)bC)[cg];
  #pragma unroll 1
  for (int k2 = 0; k2 < 32; k2++) {
    float acc = bR[k2];
    #pragma unroll
    for (int k = 0; k < 64; k++) acc = fmaf(r1[k], wR[k*32 + k2], acc);
    float r2v = fmaxf(acc, 0.f);
    #pragma unroll
    for (int cg = 0; cg < 8; cg++) {
      float4 wv = *(const float4*)&wC[k2*32 + cg*4];
      rel4[cg].x = fmaf(r2v, wv.x, rel4[cg].x);
      rel4[cg].y = fmaf(r2v, wv.y, rel4[cg].y);
      rel4[cg].z = fmaf(r2v, wv.z, rel4[cg].z);
      rel4[cg].w = fmaf(r2v, wv.w, rel4[cg].w);
    }
  }
  #pragma unroll
  for (int cg = 0; cg < 8; cg++) {
    rel4[cg].x *= att; rel4[cg].y *= att;
    rel4[cg].z *= att; rel4[cg].w *= att;
  }

  // ---- reduce over the 128 j-threads (wave butterfly + LDS combine) ----
  #pragma unroll
  for (int m = 1; m < 64; m <<= 1) {
    #pragma unroll
    for (int cg = 0; cg < 8; cg++) {
      rel4[cg].x += __shfl_xor(rel4[cg].x, m);
      rel4[cg].y += __shfl_xor(rel4[cg].y, m);
      rel4[cg].z += __shfl_xor(rel4[cg].z, m);
      rel4[cg].w += __shfl_xor(rel4[cg].w, m);
    }
  }
  int wv_ = tid >> 6, lane = tid & 63;
  if (lane == 0) {
    #pragma unroll
    for (int cg = 0; cg < 8; cg++) {
      red[wv_*32 + cg*4 + 0] = rel4[cg].x;
      red[wv_*32 + cg*4 + 1] = rel4[cg].y;
      red[wv_*32 + cg*4 + 2] = rel4[cg].z;
      red[wv_*32 + cg*4 + 3] = rel4[cg].w;
    }
  }
  __syncthreads();

  // ---- per-object tail (32 threads, LDS intermediates) ----
  if (tid < 32) {
    float d = SD_in[(size_t)bi*32 + tid] + red[tid] + red[32 + tid];
    v0_sh[tid] = d;                                    // dyn
  }
  __syncthreads();
  if (tid < 32) {
    float acc = w.af0b[tid];
    for (int k = 0; k < 32; k++) acc += v0_sh[k] * w.af0w[k*32 + tid];
    v1_sh[tid] = fast_tanh(acc);                       // aff1
  }
  __syncthreads();
  if (tid < 32) {
    float acc = w.af1b[tid];
    for (int k = 0; k < 32; k++) acc += v1_sh[k] * w.af1w[k*32 + tid];
    v2_sh[tid] = fast_tanh(acc) + v1_sh[tid];          // aff2
  }
  __syncthreads();
  if (tid < 32) {
    float acc = w.af2b[tid];
    for (int k = 0; k < 32; k++) acc += v2_sh[k] * w.af2w[k*32 + tid];
    v0_sh[tid] = acc;                                  // aff3 (reuse)
  }
  __syncthreads();
  if (tid < 32) {
    float acc = w.o0b[tid];
    for (int k = 0; k < 32; k++) acc += v0_sh[k] * w.o0w[k*32 + tid];
    for (int k = 0; k < 32; k++) acc += s_sh[k]  * w.o0w[(32+k)*32 + tid];
    v1_sh[tid] = fast_tanh(acc);                       // out1 (reuse)
  }
  __syncthreads();
  if (tid < 32) {
    float acc = w.o1b[tid] + v1_sh[tid];
    for (int k = 0; k < 32; k++) acc += v1_sh[k] * w.o1w[k*32 + tid];
    if (tid < 2) acc += s_sh[tid];
    snew_sh[tid] = acc;
    S_out[(size_t)bi*32 + tid] = acc;
    if (tid < 4)
      out_roll[(size_t)((b*NROLL + tstep)*NOBJ + i)*4 + tid] = acc;
  }
  __syncthreads();

  // ---- fused projections of the NEW state for the next step ----
  project_body(tid, bi, snew_sh, h_sh, w,
               SD_out, P1R_out, P1A_out, P2R_out, P2A_out, PX_out, PY_out);
}

// ---------------------------------------------------------------------------
extern "C" void kernel_launch(void* const* d_in, const int* in_sizes, int n_in,
                              void* d_out, int out_size, void* d_ws, size_t ws_size,
                              hipStream_t stream)
{
  const float* x    = (const float*)d_in[0];
  const float* sew  = (const float*)d_in[1];
  const float* seb  = (const float*)d_in[2];
  W w;
  w.sc0w=(const float*)d_in[3];  w.sc0b=(const float*)d_in[4];
  w.sc1w=(const float*)d_in[5];  w.sc1b=(const float*)d_in[6];
  w.rc0w=(const float*)d_in[7];  w.rc0b=(const float*)d_in[8];
  w.rc1w=(const float*)d_in[9];  w.rc1b=(const float*)d_in[10];
  w.rc2w=(const float*)d_in[11]; w.rc2b=(const float*)d_in[12];
  w.at0w=(const float*)d_in[13]; w.at0b=(const float*)d_in[14];
  w.at1w=(const float*)d_in[15]; w.at1b=(const float*)d_in[16];
  w.at2w=(const float*)d_in[17]; w.at2b=(const float*)d_in[18];
  w.af0w=(const float*)d_in[19]; w.af0b=(const float*)d_in[20];
  w.af1w=(const float*)d_in[21]; w.af1b=(const float*)d_in[22];
  w.af2w=(const float*)d_in[23]; w.af2b=(const float*)d_in[24];
  w.o0w =(const float*)d_in[25]; w.o0b =(const float*)d_in[26];
  w.o1w =(const float*)d_in[27]; w.o1b =(const float*)d_in[28];

  float* out = (float*)d_out;
  float* out_roll    = out;                              // (16,8,128,4)
  float* out_present = out + NB*NROLL*NOBJ*4;            // (16,4,128,4)

  float* ws = (float*)d_ws;
  size_t off = 0;
  auto alloc = [&](size_t n){ float* p = ws + off; off += n; return p; };
  float* S[2]   = { alloc(NB*NOBJ*32), alloc(NB*NOBJ*32) };
  float* SD[2]  = { alloc(NB*NOBJ*32), alloc(NB*NOBJ*32) };
  float* P1R[2] = { alloc(NB*NOBJ*64), alloc(NB*NOBJ*64) };
  float* P1A[2] = { alloc(NB*NOBJ*64), alloc(NB*NOBJ*64) };
  float* P2R[2] = { alloc(NB*64*NOBJ), alloc(NB*64*NOBJ) };
  float* P2A[2] = { alloc(NB*64*NOBJ), alloc(NB*64*NOBJ) };
  float* PX[2]  = { alloc(NB*NOBJ),    alloc(NB*NOBJ) };
  float* PY[2]  = { alloc(NB*NOBJ),    alloc(NB*NOBJ) };
  (void)ws_size; (void)in_sizes; (void)n_in; (void)out_size;

  hipLaunchKernelGGL(encode_kernel, dim3(NB*4), dim3(NOBJ), 0, stream,
                     x, sew, seb, out_present, S[0]);
  hipLaunchKernelGGL(project_kernel, dim3(NB*NOBJ), dim3(64), 0, stream,
                     S[0], w, SD[0], P1R[0], P1A[0], P2R[0], P2A[0], PX[0], PY[0]);

  for (int t = 0; t < NROLL; t++) {
    int a = t & 1, oo = 1 - a;
    hipLaunchKernelGGL(step_kernel, dim3(NB*NOBJ), dim3(128), 0, stream,
                       S[a], SD[a], P1R[a], P1A[a], P2R[a], P2A[a], PX[a], PY[a],
                       S[oo], SD[oo], P1R[oo], P1A[oo], P2R[oo], P2A[oo], PX[oo], PY[oo],
                       w, out_roll, t);
  }
}

// Round 3
// 841.910 us; speedup vs baseline: 9.4222x; 1.3906x over previous
//
#include <hip/hip_runtime.h>
#include <math.h>

#define NB 16
#define NOBJ 128
#define NROLL 8

struct W {
  const float *rc0w,*rc0b,*rc1w,*rc1b,*rc2w,*rc2b;
  const float *at0w,*at0b,*at1w,*at1b,*at2w,*at2b;
  const float *af0w,*af0b,*af1w,*af1b,*af2w,*af2b;
  const float *o0w,*o0b,*o1w,*o1b;
  const float *sc0w,*sc0b,*sc1w,*sc1b;
};

__device__ __forceinline__ float fast_tanh(float x){
  x = fminf(fmaxf(x, -15.f), 15.f);
  float e = __expf(2.f * x);
  return __fdividef(e - 1.f, e + 1.f);
}

// ---------------------------------------------------------------------------
__global__ __launch_bounds__(128)
void encode_kernel(const float* __restrict__ x, const float* __restrict__ sew,
                   const float* __restrict__ seb, float* __restrict__ present,
                   float* __restrict__ S0)
{
  int bt = blockIdx.x;        // b*4 + t
  int o  = threadIdx.x;       // 0..127
  const float* xv = x + (size_t)(bt * NOBJ + o) * 4;
  float x0 = xv[0], x1 = xv[1], x2 = xv[2], x3 = xv[3];
  float* pr = present + (size_t)(bt * NOBJ + o) * 4;
  pr[0] = x0; pr[1] = x1; pr[2] = x2; pr[3] = x3;
  int t = bt & 3, b = bt >> 2;
  if (t == 3) {
    float* s = S0 + (size_t)(b * NOBJ + o) * 32;
    s[0] = x0; s[1] = x1; s[2] = x2; s[3] = x3;
    #pragma unroll
    for (int k = 4; k < 32; k++)
      s[k] = seb[k] + x0*sew[k] + x1*sew[32+k] + x2*sew[64+k] + x3*sew[96+k];
  }
}

// ---------------------------------------------------------------------------
__device__ void project_body(int tid, int bo, const float* __restrict__ s_sh,
                             float* __restrict__ h_sh, const W& w,
                             float* __restrict__ SD,
                             float* __restrict__ P1R, float* __restrict__ P1A,
                             float* __restrict__ P2R, float* __restrict__ P2A,
                             float* __restrict__ PX, float* __restrict__ PY)
{
  int b = bo >> 7, o = bo & 127;
  if (tid < 64) {
    float a1r = w.rc0b[tid], a2r = 0.f, a1a = w.at0b[tid], a2a = 0.f;
    #pragma unroll
    for (int c = 0; c < 32; c++) {
      float sv = s_sh[c];
      a1r += sv * w.rc0w[c*64 + tid];
      a2r += sv * w.rc0w[(32+c)*64 + tid];
      a1a += sv * w.at0w[c*64 + tid];
      a2a += sv * w.at0w[(32+c)*64 + tid];
    }
    P1R[(size_t)bo*64 + tid] = a1r;
    P1A[(size_t)bo*64 + tid] = a1a;
    P2R[(size_t)(b*64 + tid)*NOBJ + o] = a2r;  // transposed [b][k][j]
    P2A[(size_t)(b*64 + tid)*NOBJ + o] = a2a;
  }
  if (tid < 32) {
    float acc = w.sc0b[tid];
    #pragma unroll
    for (int c = 0; c < 32; c++) acc += s_sh[c] * w.sc0w[c*32 + tid];
    h_sh[tid] = fmaxf(acc, 0.f);
  }
  __syncthreads();
  if (tid < 32) {
    float acc = w.sc1b[tid] + h_sh[tid];
    #pragma unroll
    for (int c = 0; c < 32; c++) acc += h_sh[c] * w.sc1w[c*32 + tid];
    SD[(size_t)bo*32 + tid] = acc;
  }
  if (tid == 0) { PX[bo] = s_sh[0]; PY[bo] = s_sh[1]; }
}

__global__ __launch_bounds__(64)
void project_kernel(const float* __restrict__ S, W w,
                    float* SD, float* P1R, float* P1A,
                    float* P2R, float* P2A, float* PX, float* PY)
{
  __shared__ float s_sh[32], h_sh[32];
  int bo = blockIdx.x, tid = threadIdx.x;
  if (tid < 32) s_sh[tid] = S[(size_t)bo*32 + tid];
  __syncthreads();
  project_body(tid, bo, s_sh, h_sh, w, SD, P1R, P1A, P2R, P2A, PX, PY);
}

// ---------------------------------------------------------------------------
// one rollout step.  block = (b, pair of i), 256 threads: g = tid>>7 selects
// i = pair*2+g, lt = tid&127 is j.  Weights staged once per block in LDS.
// GEMVs: float4 output groups, 2-way k-split accumulators, b128 LDS reads.
// ---------------------------------------------------------------------------
__global__ __launch_bounds__(256)
void step_kernel(const float* __restrict__ S_in,  const float* __restrict__ SD_in,
                 const float* __restrict__ P1R_in, const float* __restrict__ P1A_in,
                 const float* __restrict__ P2R_in, const float* __restrict__ P2A_in,
                 const float* __restrict__ PX_in,  const float* __restrict__ PY_in,
                 float* __restrict__ S_out, float* __restrict__ SD_out,
                 float* __restrict__ P1R_out, float* __restrict__ P1A_out,
                 float* __restrict__ P2R_out, float* __restrict__ P2A_out,
                 float* __restrict__ PX_out, float* __restrict__ PY_out,
                 W w, float* __restrict__ out_roll, int tstep)
{
  __shared__ __align__(16) float smem[6400];
  float* wA   = smem;          // 2048  at1w [64][32]
  float* wR   = smem + 2048;   // 2048  rc1w [64][32]
  float* wC   = smem + 4096;   // 1024  rc2w + I
  float* geoA = smem + 5120;   // 192   at0w rows 64..66
  float* geoR = smem + 5312;   // 192   rc0w rows 64..66
  float* bA   = smem + 5504;   // 32    at1b
  float* bR   = smem + 5536;   // 32    rc1b
  float* bC   = smem + 5568;   // 32    rc2b
  float* wT2  = smem + 5600;   // 32    at2w
  // per-group arrays (g = 0,1), 384 floats each
  float* grp  = smem + 5632;

  int tid = threadIdx.x;
  int g  = tid >> 7;           // which object of the pair
  int lt = tid & 127;          // j
  int j  = lt;
  int bp = blockIdx.x;         // b*64 + pair
  int b  = bp >> 6;
  int i  = ((bp & 63) << 1) | g;
  int bi = b * NOBJ + i;

  float* p1a_sh  = grp + g*384;        // 64
  float* p1r_sh  = grp + g*384 + 64;   // 64
  float* s_sh    = grp + g*384 + 128;  // 32
  float* snew_sh = grp + g*384 + 160;  // 32
  float* h_sh    = grp + g*384 + 192;  // 32
  float* red     = grp + g*384 + 224;  // 64 (2 waves x 32)
  float* v0_sh   = grp + g*384 + 288;  // 32
  float* v1_sh   = grp + g*384 + 320;  // 32
  float* v2_sh   = grp + g*384 + 352;  // 32

  // ---- stage weights & per-object vectors into LDS ----
  #pragma unroll
  for (int it = 0; it < 2; it++)
    ((float4*)wA)[tid + it*256] = ((const float4*)w.at1w)[tid + it*256];
  #pragma unroll
  for (int it = 0; it < 2; it++)
    ((float4*)wR)[tid + it*256] = ((const float4*)w.rc1w)[tid + it*256];
  #pragma unroll
  for (int it = 0; it < 4; it++) {
    int idx = tid + it*256;
    int k2 = idx >> 5, c = idx & 31;
    wC[idx] = w.rc2w[idx] + ((k2 == c) ? 1.f : 0.f);   // fold +I residual
  }
  if (tid < 48)
    ((float4*)geoA)[tid] = ((const float4*)(w.at0w + 64*64))[tid];
  else if (tid >= 64 && tid < 112)
    ((float4*)geoR)[tid-64] = ((const float4*)(w.rc0w + 64*64))[tid-64];
  else if (tid >= 128 && tid < 160) {
    int t = tid - 128;
    bA[t]=w.at1b[t]; bR[t]=w.rc1b[t]; bC[t]=w.rc2b[t]; wT2[t]=w.at2w[t];
  }
  if (lt < 64) { p1a_sh[lt] = P1A_in[(size_t)bi*64 + lt];
                 p1r_sh[lt] = P1R_in[(size_t)bi*64 + lt]; }
  else if (lt >= 96) s_sh[lt-96] = S_in[(size_t)bi*32 + (lt-96)];
  __syncthreads();

  float px_i = s_sh[0], py_i = s_sh[1];
  float px_j = PX_in[b*NOBJ + j], py_j = PY_in[b*NOBJ + j];
  float dx = px_i - px_j, dy = py_i - py_j;
  float dist = sqrtf(dx*dx + dy*dy + 1e-10f);

  const float* P2A_p = P2A_in + (size_t)b*64*NOBJ + j;
  const float* P2R_p = P2R_in + (size_t)b*64*NOBJ + j;

  // ---- attention path: prep (vectorized uniform LDS reads) ----
  float t1[64];
  {
    const float4* pa4 = (const float4*)p1a_sh;
    const float4* g0_ = (const float4*)geoA;
    const float4* g1_ = (const float4*)(geoA+64);
    const float4* g2_ = (const float4*)(geoA+128);
    #pragma unroll
    for (int kq = 0; kq < 16; kq++) {
      float4 pa = pa4[kq], g0 = g0_[kq], g1 = g1_[kq], g2 = g2_[kq];
      t1[4*kq+0] = fast_tanh(pa.x + P2A_p[(4*kq+0)*NOBJ] + dist*g0.x + dx*g1.x + dy*g2.x);
      t1[4*kq+1] = fast_tanh(pa.y + P2A_p[(4*kq+1)*NOBJ] + dist*g0.y + dx*g1.y + dy*g2.y);
      t1[4*kq+2] = fast_tanh(pa.z + P2A_p[(4*kq+2)*NOBJ] + dist*g0.z + dx*g1.z + dy*g2.z);
      t1[4*kq+3] = fast_tanh(pa.w + P2A_p[(4*kq+3)*NOBJ] + dist*g0.w + dx*g1.w + dy*g2.w);
    }
  }
  // att1: 64->32 tanh, float4 outputs, 2-way k-split; then 32->1
  float att_acc = w.at2b[0];
  #pragma unroll 2
  for (int k2 = 0; k2 < 32; k2 += 4) {
    float4 a0 = *(const float4*)&bA[k2];
    float4 a1 = make_float4(0.f,0.f,0.f,0.f);
    #pragma unroll
    for (int k = 0; k < 32; k++) {
      float4 w0 = *(const float4*)&wA[k*32 + k2];
      float4 w1 = *(const float4*)&wA[(k+32)*32 + k2];
      a0.x = fmaf(t1[k],    w0.x, a0.x); a0.y = fmaf(t1[k],    w0.y, a0.y);
      a0.z = fmaf(t1[k],    w0.z, a0.z); a0.w = fmaf(t1[k],    w0.w, a0.w);
      a1.x = fmaf(t1[k+32], w1.x, a1.x); a1.y = fmaf(t1[k+32], w1.y, a1.y);
      a1.z = fmaf(t1[k+32], w1.z, a1.z); a1.w = fmaf(t1[k+32], w1.w, a1.w);
    }
    att_acc += fast_tanh(a0.x+a1.x)*wT2[k2]   + fast_tanh(a0.y+a1.y)*wT2[k2+1]
             + fast_tanh(a0.z+a1.z)*wT2[k2+2] + fast_tanh(a0.w+a1.w)*wT2[k2+3];
  }
  float att = __expf(att_acc);
  if (j == i) att = 0.f;   // diag mask

  // ---- relation path: prep ----
  float r1[64];
  {
    const float4* pr4 = (const float4*)p1r_sh;
    const float4* g0_ = (const float4*)geoR;
    const float4* g1_ = (const float4*)(geoR+64);
    const float4* g2_ = (const float4*)(geoR+128);
    #pragma unroll
    for (int kq = 0; kq < 16; kq++) {
      float4 pa = pr4[kq], g0 = g0_[kq], g1 = g1_[kq], g2 = g2_[kq];
      r1[4*kq+0] = fmaxf(pa.x + P2R_p[(4*kq+0)*NOBJ] + dist*g0.x + dx*g1.x + dy*g2.x, 0.f);
      r1[4*kq+1] = fmaxf(pa.y + P2R_p[(4*kq+1)*NOBJ] + dist*g0.y + dx*g1.y + dy*g2.y, 0.f);
      r1[4*kq+2] = fmaxf(pa.z + P2R_p[(4*kq+2)*NOBJ] + dist*g0.z + dx*g1.z + dy*g2.z, 0.f);
      r1[4*kq+3] = fmaxf(pa.w + P2R_p[(4*kq+3)*NOBJ] + dist*g0.w + dx*g1.w + dy*g2.w, 0.f);
    }
  }
  // rel1 (64->32 relu) fused with rel2 (32->32, +I folded into wC)
  float4 rel4[8];
  #pragma unroll
  for (int cg = 0; cg < 8; cg++) rel4[cg] = ((const float4*)bC)[cg];
  #pragma unroll 2
  for (int k2 = 0; k2 < 32; k2 += 4) {
    float4 a0 = *(const float4*)&bR[k2];
    float4 a1 = make_float4(0.f,0.f,0.f,0.f);
    #pragma unroll
    for (int k = 0; k < 32; k++) {
      float4 w0 = *(const float4*)&wR[k*32 + k2];
      float4 w1 = *(const float4*)&wR[(k+32)*32 + k2];
      a0.x = fmaf(r1[k],    w0.x, a0.x); a0.y = fmaf(r1[k],    w0.y, a0.y);
      a0.z = fmaf(r1[k],    w0.z, a0.z); a0.w = fmaf(r1[k],    w0.w, a0.w);
      a1.x = fmaf(r1[k+32], w1.x, a1.x); a1.y = fmaf(r1[k+32], w1.y, a1.y);
      a1.z = fmaf(r1[k+32], w1.z, a1.z); a1.w = fmaf(r1[k+32], w1.w, a1.w);
    }
    float4 v;
    v.x = fmaxf(a0.x+a1.x, 0.f); v.y = fmaxf(a0.y+a1.y, 0.f);
    v.z = fmaxf(a0.z+a1.z, 0.f); v.w = fmaxf(a0.w+a1.w, 0.f);
    #pragma unroll
    for (int cg = 0; cg < 8; cg++) {
      float4 w0 = *(const float4*)&wC[(k2+0)*32 + cg*4];
      float4 w1 = *(const float4*)&wC[(k2+1)*32 + cg*4];
      float4 w2 = *(const float4*)&wC[(k2+2)*32 + cg*4];
      float4 w3 = *(const float4*)&wC[(k2+3)*32 + cg*4];
      rel4[cg].x = fmaf(v.x, w0.x, fmaf(v.y, w1.x, fmaf(v.z, w2.x, fmaf(v.w, w3.x, rel4[cg].x))));
      rel4[cg].y = fmaf(v.x, w0.y, fmaf(v.y, w1.y, fmaf(v.z, w2.y, fmaf(v.w, w3.y, rel4[cg].y))));
      rel4[cg].z = fmaf(v.x, w0.z, fmaf(v.y, w1.z, fmaf(v.z, w2.z, fmaf(v.w, w3.z, rel4[cg].z))));
      rel4[cg].w = fmaf(v.x, w0.w, fmaf(v.y, w1.w, fmaf(v.z, w2.w, fmaf(v.w, w3.w, rel4[cg].w))));
    }
  }
  #pragma unroll
  for (int cg = 0; cg < 8; cg++) {
    rel4[cg].x *= att; rel4[cg].y *= att;
    rel4[cg].z *= att; rel4[cg].w *= att;
  }

  // ---- reduce over 128 j-threads (wave butterfly + LDS combine) ----
  #pragma unroll
  for (int m = 1; m < 64; m <<= 1) {
    #pragma unroll
    for (int cg = 0; cg < 8; cg++) {
      rel4[cg].x += __shfl_xor(rel4[cg].x, m);
      rel4[cg].y += __shfl_xor(rel4[cg].y, m);
      rel4[cg].z += __shfl_xor(rel4[cg].z, m);
      rel4[cg].w += __shfl_xor(rel4[cg].w, m);
    }
  }
  int wv_ = lt >> 6, lane = tid & 63;
  if (lane == 0) {
    #pragma unroll
    for (int cg = 0; cg < 8; cg++) {
      red[wv_*32 + cg*4 + 0] = rel4[cg].x;
      red[wv_*32 + cg*4 + 1] = rel4[cg].y;
      red[wv_*32 + cg*4 + 2] = rel4[cg].z;
      red[wv_*32 + cg*4 + 3] = rel4[cg].w;
    }
  }
  __syncthreads();

  // ---- per-object tail (32 threads per group, LDS intermediates) ----
  if (lt < 32) {
    float d = SD_in[(size_t)bi*32 + lt] + red[lt] + red[32 + lt];
    v0_sh[lt] = d;                                    // dyn
  }
  __syncthreads();
  if (lt < 32) {
    float acc = w.af0b[lt];
    for (int k = 0; k < 32; k++) acc += v0_sh[k] * w.af0w[k*32 + lt];
    v1_sh[lt] = fast_tanh(acc);                       // aff1
  }
  __syncthreads();
  if (lt < 32) {
    float acc = w.af1b[lt];
    for (int k = 0; k < 32; k++) acc += v1_sh[k] * w.af1w[k*32 + lt];
    v2_sh[lt] = fast_tanh(acc) + v1_sh[lt];           // aff2
  }
  __syncthreads();
  if (lt < 32) {
    float acc = w.af2b[lt];
    for (int k = 0; k < 32; k++) acc += v2_sh[k] * w.af2w[k*32 + lt];
    v0_sh[lt] = acc;                                  // aff3 (reuse)
  }
  __syncthreads();
  if (lt < 32) {
    float acc = w.o0b[lt];
    for (int k = 0; k < 32; k++) acc += v0_sh[k] * w.o0w[k*32 + lt];
    for (int k = 0; k < 32; k++) acc += s_sh[k]  * w.o0w[(32+k)*32 + lt];
    v1_sh[lt] = fast_tanh(acc);                       // out1 (reuse)
  }
  __syncthreads();
  if (lt < 32) {
    float acc = w.o1b[lt] + v1_sh[lt];
    for (int k = 0; k < 32; k++) acc += v1_sh[k] * w.o1w[k*32 + lt];
    if (lt < 2) acc += s_sh[lt];
    snew_sh[lt] = acc;
    S_out[(size_t)bi*32 + lt] = acc;
    if (lt < 4)
      out_roll[(size_t)((b*NROLL + tstep)*NOBJ + i)*4 + lt] = acc;
  }
  __syncthreads();

  // ---- fused projections of the NEW state for the next step ----
  project_body(lt, bi, snew_sh, h_sh, w,
               SD_out, P1R_out, P1A_out, P2R_out, P2A_out, PX_out, PY_out);
}

// ---------------------------------------------------------------------------
extern "C" void kernel_launch(void* const* d_in, const int* in_sizes, int n_in,
                              void* d_out, int out_size, void* d_ws, size_t ws_size,
                              hipStream_t stream)
{
  const float* x    = (const float*)d_in[0];
  const float* sew  = (const float*)d_in[1];
  const float* seb  = (const float*)d_in[2];
  W w;
  w.sc0w=(const float*)d_in[3];  w.sc0b=(const float*)d_in[4];
  w.sc1w=(const float*)d_in[5];  w.sc1b=(const float*)d_in[6];
  w.rc0w=(const float*)d_in[7];  w.rc0b=(const float*)d_in[8];
  w.rc1w=(const float*)d_in[9];  w.rc1b=(const float*)d_in[10];
  w.rc2w=(const float*)d_in[11]; w.rc2b=(const float*)d_in[12];
  w.at0w=(const float*)d_in[13]; w.at0b=(const float*)d_in[14];
  w.at1w=(const float*)d_in[15]; w.at1b=(const float*)d_in[16];
  w.at2w=(const float*)d_in[17]; w.at2b=(const float*)d_in[18];
  w.af0w=(const float*)d_in[19]; w.af0b=(const float*)d_in[20];
  w.af1w=(const float*)d_in[21]; w.af1b=(const float*)d_in[22];
  w.af2w=(const float*)d_in[23]; w.af2b=(const float*)d_in[24];
  w.o0w =(const float*)d_in[25]; w.o0b =(const float*)d_in[26];
  w.o1w =(const float*)d_in[27]; w.o1b =(const float*)d_in[28];

  float* out = (float*)d_out;
  float* out_roll    = out;                              // (16,8,128,4)
  float* out_present = out + NB*NROLL*NOBJ*4;            // (16,4,128,4)

  float* ws = (float*)d_ws;
  size_t off = 0;
  auto alloc = [&](size_t n){ float* p = ws + off; off += n; return p; };
  float* S[2]   = { alloc(NB*NOBJ*32), alloc(NB*NOBJ*32) };
  float* SD[2]  = { alloc(NB*NOBJ*32), alloc(NB*NOBJ*32) };
  float* P1R[2] = { alloc(NB*NOBJ*64), alloc(NB*NOBJ*64) };
  float* P1A[2] = { alloc(NB*NOBJ*64), alloc(NB*NOBJ*64) };
  float* P2R[2] = { alloc(NB*64*NOBJ), alloc(NB*64*NOBJ) };
  float* P2A[2] = { alloc(NB*64*NOBJ), alloc(NB*64*NOBJ) };
  float* PX[2]  = { alloc(NB*NOBJ),    alloc(NB*NOBJ) };
  float* PY[2]  = { alloc(NB*NOBJ),    alloc(NB*NOBJ) };
  (void)ws_size; (void)in_sizes; (void)n_in; (void)out_size;

  hipLaunchKernelGGL(encode_kernel, dim3(NB*4), dim3(NOBJ), 0, stream,
                     x, sew, seb, out_present, S[0]);
  hipLaunchKernelGGL(project_kernel, dim3(NB*NOBJ), dim3(64), 0, stream,
                     S[0], w, SD[0], P1R[0], P1A[0], P2R[0], P2A[0], PX[0], PY[0]);

  for (int t = 0; t < NROLL; t++) {
    int a = t & 1, oo = 1 - a;
    hipLaunchKernelGGL(step_kernel, dim3(NB*NOBJ/2), dim3(256), 0, stream,
                       S[a], SD[a], P1R[a], P1A[a], P2R[a], P2A[a], PX[a], PY[a],
                       S[oo], SD[oo], P1R[oo], P1A[oo], P2R[oo], P2A[oo], PX[oo], PY[oo],
                       w, out_roll, t);
  }
}